// Round 6
// baseline (400.103 us; speedup 1.0000x reference)
//
#include <hip/hip_runtime.h>
#include <math.h>

constexpr int N = 50000;   // nodes
constexpr int E = 640000;  // edges
constexpr int D = 128;     // dim == hidden
constexpr int T = 100;     // targets per head
constexpr int NB = (N + 255) / 256;  // 196 scan blocks

typedef __attribute__((ext_vector_type(8))) short short8;            // 8 bf16 in 4 VGPRs
typedef __attribute__((ext_vector_type(8))) unsigned short ushort8v;
typedef __attribute__((ext_vector_type(4))) float f32x4;             // MFMA accumulator

// ---------------- bf16 helpers (RNE) ----------------

__device__ inline unsigned short bf16_rne(float f) {
  unsigned int u = __float_as_uint(f);
  u += 0x7fff + ((u >> 16) & 1);
  return (unsigned short)(u >> 16);
}
__device__ inline float bf16_f32(unsigned short h) {
  return __uint_as_float((unsigned int)h << 16);
}

// ---------------- fused degree+count histogram: ONE 64-bit atomic per edge ----------------
// high 32 bits: ew in 8.24 fixed point; low 32: count.

__global__ void deg_count_kernel(const float* __restrict__ ew, const int* __restrict__ dst,
                                 unsigned long long* __restrict__ degcnt) {
  int e = blockIdx.x * 256 + threadIdx.x;
  if (e < E) {
    unsigned int fx = (unsigned int)__float2uint_rn(ew[e] * 16777216.0f);
    atomicAdd(&degcnt[dst[e]], ((unsigned long long)fx << 32) | 1ull);
  }
}

// ---------------- scan phase 1 (+ dinv folded in) ----------------

__global__ __launch_bounds__(256) void scan_reduce_kernel(const uint2* __restrict__ degcnt,
                                                          int* __restrict__ bsum,
                                                          float* __restrict__ dinv) {
  __shared__ int part[256];
  int t = threadIdx.x;
  int i = blockIdx.x * 256 + t;
  int c = 0;
  if (i < N) {
    uint2 p = degcnt[i];
    c = (int)p.x;
    float d = (float)p.y * (1.0f / 16777216.0f) + 1.0f;  // +1 self-loop
    dinv[i] = 1.0f / sqrtf(d);
  }
  part[t] = c;
  __syncthreads();
#pragma unroll
  for (int off = 128; off; off >>= 1) {
    if (t < off) part[t] += part[t + off];
    __syncthreads();
  }
  if (t == 0) bsum[blockIdx.x] = part[0];
}

__global__ __launch_bounds__(256) void scan_bsum_kernel(int* __restrict__ bsum) {
  __shared__ int part[256];
  int t = threadIdx.x;
  int v = (t < NB) ? bsum[t] : 0;
  part[t] = v;
  __syncthreads();
#pragma unroll
  for (int off = 1; off < 256; off <<= 1) {
    int u = (t >= off) ? part[t - off] : 0;
    __syncthreads();
    part[t] += u;
    __syncthreads();
  }
  if (t < NB) bsum[t] = part[t] - v;  // exclusive
}

__global__ __launch_bounds__(256) void scan_apply_kernel(const uint2* __restrict__ degcnt,
                                                         const int* __restrict__ bsum,
                                                         int* __restrict__ offs,
                                                         int* __restrict__ cursor) {
  __shared__ int part[256];
  int t = threadIdx.x;
  int i = blockIdx.x * 256 + t;
  int c = (i < N) ? (int)degcnt[i].x : 0;
  part[t] = c;
  __syncthreads();
#pragma unroll
  for (int off = 1; off < 256; off <<= 1) {
    int u = (t >= off) ? part[t - off] : 0;
    __syncthreads();
    part[t] += u;
    __syncthreads();
  }
  if (i < N) {
    int o = bsum[blockIdx.x] + part[t] - c;  // exclusive
    offs[i] = o;
    cursor[i] = o;
  }
  if (i == 0) offs[N] = E;
}

// ---------------- CSR fill: 4-byte entry = (coef 0.16-fixed << 16) | src(u16) ----------------

__global__ void fill_kernel(const int* __restrict__ src, const int* __restrict__ dst,
                            const float* __restrict__ ew, const float* __restrict__ dinv,
                            int* __restrict__ cursor, unsigned int* __restrict__ csr) {
  int e = blockIdx.x * 256 + threadIdx.x;
  if (e < E) {
    int s = src[e], d = dst[e];
    float c = dinv[s] * ew[e] * dinv[d];  // in [0,1)
    unsigned int fx = __float2uint_rn(c * 65536.0f);
    if (fx > 65535u) fx = 65535u;
    int pos = atomicAdd(&cursor[d], 1);
    csr[pos] = (fx << 16) | (unsigned int)s;
  }
}

// ---------------- W prep: fp32 W[k][n] -> bf16 hi/lo transposed Wt[n][k], 4 layers ----------------

__global__ void wprep_kernel(const float* __restrict__ W0, const float* __restrict__ W1,
                             const float* __restrict__ W2, const float* __restrict__ W3,
                             unsigned short* __restrict__ wt) {
  int idx = blockIdx.x * 256 + threadIdx.x;  // 0..65535
  int layer = idx >> 14;
  int r = idx & 16383;
  int k = r & 127, n = r >> 7;
  const float* W = layer == 0 ? W0 : layer == 1 ? W1 : layer == 2 ? W2 : W3;
  float v = W[k * D + n];
  unsigned short hi = bf16_rne(v);
  unsigned short lo = bf16_rne(v - bf16_f32(hi));
  unsigned short* dstp = wt + layer * 2 * 16384;
  dstp[n * D + k] = hi;
  dstp[16384 + n * D + k] = lo;
}

// ---------------- fp32 -> bf16 hi/lo split (layer-1 input x) ----------------

__global__ void split_kernel(const float* __restrict__ in, unsigned short* __restrict__ hi,
                             unsigned short* __restrict__ lo) {
  int i = blockIdx.x * 256 + threadIdx.x;  // 8 floats per thread; N*D/8 threads exact
  const float4* in4 = (const float4*)in;
  float4 a = in4[2 * i], b = in4[2 * i + 1];
  ushort8v h, l;
  float v[8] = {a.x, a.y, a.z, a.w, b.x, b.y, b.z, b.w};
#pragma unroll
  for (int j = 0; j < 8; ++j) {
    h[j] = bf16_rne(v[j]);
    l[j] = bf16_rne(v[j] - bf16_f32(h[j]));
  }
  *(ushort8v*)&hi[(size_t)i * 8] = h;
  *(ushort8v*)&lo[(size_t)i * 8] = l;
}

// ---------------- split-bf16 MFMA GEMM, no LDS: frags loaded straight from global ----------------
// A given as hi/lo bf16 planes [N][128] row-major. 64 rows/block, 4 waves:
// wave w -> rows 32*(w&1)+[0,32), cols 64*(w>>1)+[0,64).
// A·B = Ahi·Bhi + Alo·Bhi + Ahi·Blo. out_bf16=1 -> bf16 (feeds agg); else fp32.

__global__ __launch_bounds__(256) void gemm_mfma_kernel(
    const unsigned short* __restrict__ Ahi, const unsigned short* __restrict__ Alo,
    const unsigned short* __restrict__ Wt, const float* __restrict__ bias,
    void* __restrict__ out, int relu, int out_bf16) {
  const int tid = threadIdx.x;
  const int row0 = blockIdx.x * 64;
  const int w = tid >> 6, lane = tid & 63;
  const int q = lane >> 4, n16 = lane & 15;
  const int rbase = (w & 1) * 32;
  const int cbase = (w >> 1) * 64;

  size_t arow[2];
#pragma unroll
  for (int rt = 0; rt < 2; ++rt) {
    int gr = row0 + rbase + rt * 16 + n16;
    if (gr >= N) gr = N - 1;           // clamp reads; stores guarded below
    arow[rt] = (size_t)gr * D;
  }

  f32x4 acc[2][4] = {{{0.f, 0.f, 0.f, 0.f}, {0.f, 0.f, 0.f, 0.f},
                      {0.f, 0.f, 0.f, 0.f}, {0.f, 0.f, 0.f, 0.f}},
                     {{0.f, 0.f, 0.f, 0.f}, {0.f, 0.f, 0.f, 0.f},
                      {0.f, 0.f, 0.f, 0.f}, {0.f, 0.f, 0.f, 0.f}}};

#pragma unroll
  for (int kc = 0; kc < 4; ++kc) {
    const int ko = kc * 32 + q * 8;
    short8 ah[2], al[2];
#pragma unroll
    for (int rt = 0; rt < 2; ++rt) {
      ah[rt] = *(const short8*)&Ahi[arow[rt] + ko];
      al[rt] = *(const short8*)&Alo[arow[rt] + ko];
    }
#pragma unroll
    for (int ct = 0; ct < 4; ++ct) {
      int n = cbase + ct * 16 + n16;
      short8 bh = *(const short8*)&Wt[n * D + ko];
      short8 bl = *(const short8*)&Wt[16384 + n * D + ko];
#pragma unroll
      for (int rt = 0; rt < 2; ++rt) {
        acc[rt][ct] = __builtin_amdgcn_mfma_f32_16x16x32_bf16(ah[rt], bh, acc[rt][ct], 0, 0, 0);
        acc[rt][ct] = __builtin_amdgcn_mfma_f32_16x16x32_bf16(al[rt], bh, acc[rt][ct], 0, 0, 0);
        acc[rt][ct] = __builtin_amdgcn_mfma_f32_16x16x32_bf16(ah[rt], bl, acc[rt][ct], 0, 0, 0);
      }
    }
  }

  // epilogue: C/D layout col=lane&15, row=(lane>>4)*4+reg
#pragma unroll
  for (int rt = 0; rt < 2; ++rt) {
#pragma unroll
    for (int r = 0; r < 4; ++r) {
      int gr = row0 + rbase + rt * 16 + q * 4 + r;
      if (gr < N) {
#pragma unroll
        for (int ct = 0; ct < 4; ++ct) {
          int col = cbase + ct * 16 + n16;
          float v = acc[rt][ct][r];
          if (bias) v += bias[col];
          if (relu) v = fmaxf(v, 0.f);
          if (out_bf16) ((unsigned short*)out)[(size_t)gr * D + col] = bf16_rne(v);
          else          ((float*)out)[(size_t)gr * D + col] = v;
        }
      }
    }
  }
}

// ---------------- pull aggregation over bf16 xw; writes bf16 hi/lo planes ----------------
// acc = dinv^2*xw[n] + b + sum coef*xw[src]; relu; split to hi/lo for the next GEMM.
// 16 lanes/node, 8 bf16 per lane (16B gathers).

__global__ __launch_bounds__(256) void agg_kernel(
    const unsigned short* __restrict__ xwb, const unsigned int* __restrict__ csr,
    const int* __restrict__ offs, const float* __restrict__ dinv,
    const float* __restrict__ bias, unsigned short* __restrict__ ohi,
    unsigned short* __restrict__ olo) {
  int g = (blockIdx.x * 256 + threadIdx.x) >> 4;  // node; 16 nodes/block
  int lane = threadIdx.x & 15;

  float dv = dinv[g];
  float s = dv * dv;
  ushort8v xv = *(const ushort8v*)&xwb[(size_t)g * D + lane * 8];
  float acc[8];
#pragma unroll
  for (int i = 0; i < 8; ++i)
    acc[i] = fmaf(s, bf16_f32(xv[i]), bias[lane * 8 + i]);

  int e = offs[g], e1 = offs[g + 1];
  for (; e + 2 <= e1; e += 2) {
    unsigned int p0 = csr[e], p1 = csr[e + 1];
    float c0 = (float)(p0 >> 16) * (1.0f / 65536.0f);
    float c1 = (float)(p1 >> 16) * (1.0f / 65536.0f);
    ushort8v v0 = *(const ushort8v*)&xwb[(size_t)(p0 & 0xffffu) * D + lane * 8];
    ushort8v v1 = *(const ushort8v*)&xwb[(size_t)(p1 & 0xffffu) * D + lane * 8];
#pragma unroll
    for (int i = 0; i < 8; ++i) {
      acc[i] = fmaf(c0, bf16_f32(v0[i]), acc[i]);
      acc[i] = fmaf(c1, bf16_f32(v1[i]), acc[i]);
    }
  }
  if (e < e1) {
    unsigned int p = csr[e];
    float c = (float)(p >> 16) * (1.0f / 65536.0f);
    ushort8v v = *(const ushort8v*)&xwb[(size_t)(p & 0xffffu) * D + lane * 8];
#pragma unroll
    for (int i = 0; i < 8; ++i) acc[i] = fmaf(c, bf16_f32(v[i]), acc[i]);
  }

  ushort8v hv, lv;
#pragma unroll
  for (int i = 0; i < 8; ++i) {
    float v = fmaxf(acc[i], 0.f);
    hv[i] = bf16_rne(v);
    lv[i] = bf16_rne(v - bf16_f32(hv[i]));
  }
  *(ushort8v*)&ohi[(size_t)g * D + lane * 8] = hv;
  *(ushort8v*)&olo[(size_t)g * D + lane * 8] = lv;
}

// ---------------- heads ----------------

__global__ void heads_kernel(const float* __restrict__ h,
                             const int* __restrict__ ace_idx, const int* __restrict__ h2_idx,
                             const float* __restrict__ Wace, const float* __restrict__ bace,
                             const float* __restrict__ Wh2, const float* __restrict__ bh2,
                             float* __restrict__ out) {
  int t = blockIdx.x;
  int lane = threadIdx.x;
  int node; const float* w; float b;
  if (t < T) { node = ace_idx[t];     w = Wace; b = bace[0]; }
  else       { node = h2_idx[t - T];  w = Wh2;  b = bh2[0]; }
  const float* hr = h + node * D;
  float v = hr[lane] * w[lane] + hr[lane + 64] * w[lane + 64];
#pragma unroll
  for (int off = 32; off; off >>= 1) v += __shfl_down(v, off, 64);
  if (lane == 0) out[t] = v + b;
}

// ---------------- launch ----------------

extern "C" void kernel_launch(void* const* d_in, const int* in_sizes, int n_in,
                              void* d_out, int out_size, void* d_ws, size_t ws_size,
                              hipStream_t stream) {
  const float* x    = (const float*)d_in[0];
  const int*   ei   = (const int*)d_in[1];
  const float* ew   = (const float*)d_in[2];
  const int*   ace  = (const int*)d_in[3];
  const int*   h2   = (const int*)d_in[4];
  const float* W1 = (const float*)d_in[5];  const float* b1 = (const float*)d_in[6];
  const float* W2 = (const float*)d_in[7];  const float* b2 = (const float*)d_in[8];
  const float* W3 = (const float*)d_in[9];  const float* b3 = (const float*)d_in[10];
  const float* Wh = (const float*)d_in[11]; const float* bh = (const float*)d_in[12];
  const float* Wace = (const float*)d_in[13]; const float* bace = (const float*)d_in[14];
  const float* Wh2  = (const float*)d_in[15]; const float* bh2  = (const float*)d_in[16];
  const int* src = ei;
  const int* dst = ei + E;

  // workspace layout (16B-aligned blocks); ~68 MB total
  char* w = (char*)d_ws;
  unsigned long long* degcnt = (unsigned long long*)w;  w += (size_t)N * 8;  // zeroed
  float* dinv   = (float*)w;              w += N * 4;
  int*   offs   = (int*)w;                w += (N + 4) * 4;
  int*   cursor = (int*)w;                w += N * 4;
  int*   bsum   = (int*)w;                w += 256 * 4;
  unsigned short* wt = (unsigned short*)w; w += 4 * 2 * 16384 * 2;   // 4 layers hi/lo bf16
  unsigned int* csr = (unsigned int*)w;   w += (size_t)E * 4;
  unsigned short* xwb = (unsigned short*)w; w += (size_t)N * D * 2;  // bf16 GEMM out
  unsigned short* P0hi = (unsigned short*)w; w += (size_t)N * D * 2; // ping-pong planes
  unsigned short* P0lo = (unsigned short*)w; w += (size_t)N * D * 2;
  unsigned short* P1hi = (unsigned short*)w; w += (size_t)N * D * 2;
  unsigned short* P1lo = (unsigned short*)w; w += (size_t)N * D * 2;
  float* hOut = (float*)P0hi;  // alias: P0 planes dead after gemm3 (25.6 MB = P0hi+P0lo)

  // ---- graph build + prep ----
  hipMemsetAsync(degcnt, 0, (size_t)N * 8, stream);
  deg_count_kernel<<<(E + 255) / 256, 256, 0, stream>>>(ew, dst, degcnt);
  scan_reduce_kernel<<<NB, 256, 0, stream>>>((const uint2*)degcnt, bsum, dinv);
  scan_bsum_kernel<<<1, 256, 0, stream>>>(bsum);
  scan_apply_kernel<<<NB, 256, 0, stream>>>((const uint2*)degcnt, bsum, offs, cursor);
  fill_kernel<<<(E + 255) / 256, 256, 0, stream>>>(src, dst, ew, dinv, cursor, csr);
  wprep_kernel<<<256, 256, 0, stream>>>(W1, W2, W3, Wh, wt);
  split_kernel<<<N * D / 8 / 256, 256, 0, stream>>>(x, P0hi, P0lo);  // 3125 blocks exact

  const int GB = (N + 63) / 64;   // 782 gemm blocks
  const int AG = N * 16 / 256;    // 3125 agg blocks

  // layer 1: P0 -> xwb -> P1
  gemm_mfma_kernel<<<GB, 256, 0, stream>>>(P0hi, P0lo, wt + 0 * 32768, nullptr, xwb, 0, 1);
  agg_kernel<<<AG, 256, 0, stream>>>(xwb, csr, offs, dinv, b1, P1hi, P1lo);
  // layer 2: P1 -> xwb -> P0
  gemm_mfma_kernel<<<GB, 256, 0, stream>>>(P1hi, P1lo, wt + 1 * 32768, nullptr, xwb, 0, 1);
  agg_kernel<<<AG, 256, 0, stream>>>(xwb, csr, offs, dinv, b2, P0hi, P0lo);
  // layer 3: P0 -> xwb -> P1
  gemm_mfma_kernel<<<GB, 256, 0, stream>>>(P0hi, P0lo, wt + 2 * 32768, nullptr, xwb, 0, 1);
  agg_kernel<<<AG, 256, 0, stream>>>(xwb, csr, offs, dinv, b3, P1hi, P1lo);
  // dense head layer: hOut = relu(P1 @ Wh + bh), fp32 (hOut aliases P0 region)
  gemm_mfma_kernel<<<GB, 256, 0, stream>>>(P1hi, P1lo, wt + 3 * 32768, bh, hOut, 1, 0);
  // heads
  heads_kernel<<<2 * T, 64, 0, stream>>>(hOut, ace, h2, Wace, bace, Wh2, bh2, (float*)d_out);
}

// Round 7
// 349.824 us; speedup vs baseline: 1.1437x; 1.1437x over previous
//
#include <hip/hip_runtime.h>
#include <math.h>

constexpr int N = 50000;   // nodes
constexpr int E = 640000;  // edges
constexpr int D = 128;     // dim == hidden
constexpr int T = 100;     // targets per head
constexpr int NB = (N + 255) / 256;  // 196 scan blocks

typedef __attribute__((ext_vector_type(8))) short short8;            // 8 bf16 in 4 VGPRs
typedef __attribute__((ext_vector_type(8))) unsigned short ushort8v;
typedef __attribute__((ext_vector_type(4))) float f32x4;             // MFMA accumulator

// ---------------- bf16 helpers (RNE) ----------------

__device__ inline unsigned short bf16_rne(float f) {
  unsigned int u = __float_as_uint(f);
  u += 0x7fff + ((u >> 16) & 1);
  return (unsigned short)(u >> 16);
}
__device__ inline float bf16_f32(unsigned short h) {
  return __uint_as_float((unsigned int)h << 16);
}

// ---------------- fused degree+count histogram: ONE 64-bit atomic per edge ----------------

__global__ void deg_count_kernel(const float* __restrict__ ew, const int* __restrict__ dst,
                                 unsigned long long* __restrict__ degcnt) {
  int e = blockIdx.x * 256 + threadIdx.x;
  if (e < E) {
    unsigned int fx = (unsigned int)__float2uint_rn(ew[e] * 16777216.0f);
    atomicAdd(&degcnt[dst[e]], ((unsigned long long)fx << 32) | 1ull);
  }
}

// ---------------- scan phase 1 (+ dinv folded in) ----------------

__global__ __launch_bounds__(256) void scan_reduce_kernel(const uint2* __restrict__ degcnt,
                                                          int* __restrict__ bsum,
                                                          float* __restrict__ dinv) {
  __shared__ int part[256];
  int t = threadIdx.x;
  int i = blockIdx.x * 256 + t;
  int c = 0;
  if (i < N) {
    uint2 p = degcnt[i];
    c = (int)p.x;
    float d = (float)p.y * (1.0f / 16777216.0f) + 1.0f;  // +1 self-loop
    dinv[i] = 1.0f / sqrtf(d);
  }
  part[t] = c;
  __syncthreads();
#pragma unroll
  for (int off = 128; off; off >>= 1) {
    if (t < off) part[t] += part[t + off];
    __syncthreads();
  }
  if (t == 0) bsum[blockIdx.x] = part[0];
}

__global__ __launch_bounds__(256) void scan_bsum_kernel(int* __restrict__ bsum) {
  __shared__ int part[256];
  int t = threadIdx.x;
  int v = (t < NB) ? bsum[t] : 0;
  part[t] = v;
  __syncthreads();
#pragma unroll
  for (int off = 1; off < 256; off <<= 1) {
    int u = (t >= off) ? part[t - off] : 0;
    __syncthreads();
    part[t] += u;
    __syncthreads();
  }
  if (t < NB) bsum[t] = part[t] - v;  // exclusive
}

__global__ __launch_bounds__(256) void scan_apply_kernel(const uint2* __restrict__ degcnt,
                                                         const int* __restrict__ bsum,
                                                         int* __restrict__ offs,
                                                         int* __restrict__ cursor) {
  __shared__ int part[256];
  int t = threadIdx.x;
  int i = blockIdx.x * 256 + t;
  int c = (i < N) ? (int)degcnt[i].x : 0;
  part[t] = c;
  __syncthreads();
#pragma unroll
  for (int off = 1; off < 256; off <<= 1) {
    int u = (t >= off) ? part[t - off] : 0;
    __syncthreads();
    part[t] += u;
    __syncthreads();
  }
  if (i < N) {
    int o = bsum[blockIdx.x] + part[t] - c;  // exclusive
    offs[i] = o;
    cursor[i] = o;
  }
  if (i == 0) offs[N] = E;
}

// ---------------- CSR fill: 4-byte entry = (coef 0.16-fixed << 16) | src(u16) ----------------

__global__ void fill_kernel(const int* __restrict__ src, const int* __restrict__ dst,
                            const float* __restrict__ ew, const float* __restrict__ dinv,
                            int* __restrict__ cursor, unsigned int* __restrict__ csr) {
  int e = blockIdx.x * 256 + threadIdx.x;
  if (e < E) {
    int s = src[e], d = dst[e];
    float c = dinv[s] * ew[e] * dinv[d];  // in [0,1)
    unsigned int fx = __float2uint_rn(c * 65536.0f);
    if (fx > 65535u) fx = 65535u;
    int pos = atomicAdd(&cursor[d], 1);
    csr[pos] = (fx << 16) | (unsigned int)s;
  }
}

// ---------------- W prep: fp32 W[k][n] -> bf16 hi/lo transposed Wt[n][k], 4 layers ----------------

__global__ void wprep_kernel(const float* __restrict__ W0, const float* __restrict__ W1,
                             const float* __restrict__ W2, const float* __restrict__ W3,
                             unsigned short* __restrict__ wt) {
  int idx = blockIdx.x * 256 + threadIdx.x;  // 0..65535
  int layer = idx >> 14;
  int r = idx & 16383;
  int k = r & 127, n = r >> 7;
  const float* W = layer == 0 ? W0 : layer == 1 ? W1 : layer == 2 ? W2 : W3;
  float v = W[k * D + n];
  unsigned short hi = bf16_rne(v);
  unsigned short lo = bf16_rne(v - bf16_f32(hi));
  unsigned short* dstp = wt + layer * 2 * 16384;
  dstp[n * D + k] = hi;
  dstp[16384 + n * D + k] = lo;
}

// ---------------- fp32 -> bf16 hi/lo split (layer-1 input x) ----------------

__global__ void split_kernel(const float* __restrict__ in, unsigned short* __restrict__ hi,
                             unsigned short* __restrict__ lo) {
  int i = blockIdx.x * 256 + threadIdx.x;  // 8 floats per thread
  const float4* in4 = (const float4*)in;
  float4 a = in4[2 * i], b = in4[2 * i + 1];
  ushort8v h, l;
  float v[8] = {a.x, a.y, a.z, a.w, b.x, b.y, b.z, b.w};
#pragma unroll
  for (int j = 0; j < 8; ++j) {
    h[j] = bf16_rne(v[j]);
    l[j] = bf16_rne(v[j] - bf16_f32(h[j]));
  }
  *(ushort8v*)&hi[(size_t)i * 8] = h;
  *(ushort8v*)&lo[(size_t)i * 8] = l;
}

// ---------------- split-bf16 MFMA GEMM: B (hi+lo) staged in LDS, A streamed ----------------
// 128 rows/block, 4 waves; wave w: rows 32w..32w+32, all 128 cols.
// LDS: 2 planes x 128 rows x stride 136 bf16 = 69632 B -> 2 blocks/CU.
// A given as bf16 hi/lo planes [N][128] row-major (split done by producers).
// A.B = Ahi.Bhi + Alo.Bhi + Ahi.Blo. out_bf16=1 -> bf16 out (feeds agg); else fp32.

__global__ __launch_bounds__(256) void gemm_mfma_kernel(
    const unsigned short* __restrict__ Ahi, const unsigned short* __restrict__ Alo,
    const unsigned short* __restrict__ Wt, const float* __restrict__ bias,
    void* __restrict__ out, int relu, int out_bf16) {
  constexpr int SB = 136;                       // padded row stride (2-way bank alias = free)
  __shared__ unsigned short Bl[2 * 128 * SB];   // 69632 B
  const int tid = threadIdx.x;
  const int row0 = blockIdx.x * 128;

  // stage B: hi plane then lo plane, 16 iters x 256 threads x 8 bf16
#pragma unroll
  for (int it = 0; it < 16; ++it) {
    int idx = tid + it * 256;          // ushort8 index, 0..4095
    int plane = idx >> 11;             // 2048 ushort8 per plane
    int r = (idx & 2047) >> 4;         // row 0..127
    int c8 = idx & 15;                 // 16 ushort8 per row
    ushort8v v = *(const ushort8v*)&Wt[plane * 16384 + r * D + c8 * 8];
    *(ushort8v*)&Bl[plane * 128 * SB + r * SB + c8 * 8] = v;
  }
  __syncthreads();

  const int w = tid >> 6, lane = tid & 63;
  const int q = lane >> 4, n16 = lane & 15;
  const int rbase = w * 32;

  size_t arow[2];
#pragma unroll
  for (int rt = 0; rt < 2; ++rt) {
    int gr = row0 + rbase + rt * 16 + n16;
    if (gr >= N) gr = N - 1;           // clamp reads; stores guarded below
    arow[rt] = (size_t)gr * D;
  }

  f32x4 acc[2][8] = {};

#pragma unroll
  for (int kc = 0; kc < 4; ++kc) {
    const int ko = kc * 32 + q * 8;
    short8 ah[2], al[2];
#pragma unroll
    for (int rt = 0; rt < 2; ++rt) {
      ah[rt] = *(const short8*)&Ahi[arow[rt] + ko];
      al[rt] = *(const short8*)&Alo[arow[rt] + ko];
    }
#pragma unroll
    for (int ct = 0; ct < 8; ++ct) {
      int n = ct * 16 + n16;
      short8 bh = *(const short8*)&Bl[n * SB + ko];
      short8 bl = *(const short8*)&Bl[128 * SB + n * SB + ko];
#pragma unroll
      for (int rt = 0; rt < 2; ++rt) {
        acc[rt][ct] = __builtin_amdgcn_mfma_f32_16x16x32_bf16(ah[rt], bh, acc[rt][ct], 0, 0, 0);
        acc[rt][ct] = __builtin_amdgcn_mfma_f32_16x16x32_bf16(al[rt], bh, acc[rt][ct], 0, 0, 0);
        acc[rt][ct] = __builtin_amdgcn_mfma_f32_16x16x32_bf16(ah[rt], bl, acc[rt][ct], 0, 0, 0);
      }
    }
  }

  // epilogue: C/D layout col=lane&15, row=(lane>>4)*4+reg
#pragma unroll
  for (int rt = 0; rt < 2; ++rt) {
#pragma unroll
    for (int r = 0; r < 4; ++r) {
      int gr = row0 + rbase + rt * 16 + q * 4 + r;
      if (gr < N) {
#pragma unroll
        for (int ct = 0; ct < 8; ++ct) {
          int col = ct * 16 + n16;
          float v = acc[rt][ct][r];
          if (bias) v += bias[col];
          if (relu) v = fmaxf(v, 0.f);
          if (out_bf16) ((unsigned short*)out)[(size_t)gr * D + col] = bf16_rne(v);
          else          ((float*)out)[(size_t)gr * D + col] = v;
        }
      }
    }
  }
}

// ---------------- pull aggregation over bf16 xw; writes bf16 hi/lo planes ----------------
// acc = dinv^2*xw[n] + b + sum coef*xw[src]; relu; split to hi/lo for the next GEMM.
// 16 lanes/node, 8 bf16 per lane (16B gathers).

__global__ __launch_bounds__(256) void agg_kernel(
    const unsigned short* __restrict__ xwb, const unsigned int* __restrict__ csr,
    const int* __restrict__ offs, const float* __restrict__ dinv,
    const float* __restrict__ bias, unsigned short* __restrict__ ohi,
    unsigned short* __restrict__ olo) {
  int g = (blockIdx.x * 256 + threadIdx.x) >> 4;  // node; 16 nodes/block
  int lane = threadIdx.x & 15;

  float dv = dinv[g];
  float s = dv * dv;
  ushort8v xv = *(const ushort8v*)&xwb[(size_t)g * D + lane * 8];
  float acc[8];
#pragma unroll
  for (int i = 0; i < 8; ++i)
    acc[i] = fmaf(s, bf16_f32(xv[i]), bias[lane * 8 + i]);

  int e = offs[g], e1 = offs[g + 1];
  for (; e + 2 <= e1; e += 2) {
    unsigned int p0 = csr[e], p1 = csr[e + 1];
    float c0 = (float)(p0 >> 16) * (1.0f / 65536.0f);
    float c1 = (float)(p1 >> 16) * (1.0f / 65536.0f);
    ushort8v v0 = *(const ushort8v*)&xwb[(size_t)(p0 & 0xffffu) * D + lane * 8];
    ushort8v v1 = *(const ushort8v*)&xwb[(size_t)(p1 & 0xffffu) * D + lane * 8];
#pragma unroll
    for (int i = 0; i < 8; ++i) {
      acc[i] = fmaf(c0, bf16_f32(v0[i]), acc[i]);
      acc[i] = fmaf(c1, bf16_f32(v1[i]), acc[i]);
    }
  }
  if (e < e1) {
    unsigned int p = csr[e];
    float c = (float)(p >> 16) * (1.0f / 65536.0f);
    ushort8v v = *(const ushort8v*)&xwb[(size_t)(p & 0xffffu) * D + lane * 8];
#pragma unroll
    for (int i = 0; i < 8; ++i) acc[i] = fmaf(c, bf16_f32(v[i]), acc[i]);
  }

  ushort8v hv, lv;
#pragma unroll
  for (int i = 0; i < 8; ++i) {
    float v = fmaxf(acc[i], 0.f);
    hv[i] = bf16_rne(v);
    lv[i] = bf16_rne(v - bf16_f32(hv[i]));
  }
  *(ushort8v*)&ohi[(size_t)g * D + lane * 8] = hv;
  *(ushort8v*)&olo[(size_t)g * D + lane * 8] = lv;
}

// ---------------- heads ----------------

__global__ void heads_kernel(const float* __restrict__ h,
                             const int* __restrict__ ace_idx, const int* __restrict__ h2_idx,
                             const float* __restrict__ Wace, const float* __restrict__ bace,
                             const float* __restrict__ Wh2, const float* __restrict__ bh2,
                             float* __restrict__ out) {
  int t = blockIdx.x;
  int lane = threadIdx.x;
  int node; const float* w; float b;
  if (t < T) { node = ace_idx[t];     w = Wace; b = bace[0]; }
  else       { node = h2_idx[t - T];  w = Wh2;  b = bh2[0]; }
  const float* hr = h + node * D;
  float v = hr[lane] * w[lane] + hr[lane + 64] * w[lane + 64];
#pragma unroll
  for (int off = 32; off; off >>= 1) v += __shfl_down(v, off, 64);
  if (lane == 0) out[t] = v + b;
}

// ---------------- launch ----------------

extern "C" void kernel_launch(void* const* d_in, const int* in_sizes, int n_in,
                              void* d_out, int out_size, void* d_ws, size_t ws_size,
                              hipStream_t stream) {
  const float* x    = (const float*)d_in[0];
  const int*   ei   = (const int*)d_in[1];
  const float* ew   = (const float*)d_in[2];
  const int*   ace  = (const int*)d_in[3];
  const int*   h2   = (const int*)d_in[4];
  const float* W1 = (const float*)d_in[5];  const float* b1 = (const float*)d_in[6];
  const float* W2 = (const float*)d_in[7];  const float* b2 = (const float*)d_in[8];
  const float* W3 = (const float*)d_in[9];  const float* b3 = (const float*)d_in[10];
  const float* Wh = (const float*)d_in[11]; const float* bh = (const float*)d_in[12];
  const float* Wace = (const float*)d_in[13]; const float* bace = (const float*)d_in[14];
  const float* Wh2  = (const float*)d_in[15]; const float* bh2  = (const float*)d_in[16];
  const int* src = ei;
  const int* dst = ei + E;

  // workspace layout (16B-aligned blocks); ~68 MB total
  char* w = (char*)d_ws;
  unsigned long long* degcnt = (unsigned long long*)w;  w += (size_t)N * 8;  // zeroed
  float* dinv   = (float*)w;              w += N * 4;
  int*   offs   = (int*)w;                w += (N + 4) * 4;
  int*   cursor = (int*)w;                w += N * 4;
  int*   bsum   = (int*)w;                w += 256 * 4;
  unsigned short* wt = (unsigned short*)w; w += 4 * 2 * 16384 * 2;   // 4 layers hi/lo bf16
  unsigned int* csr = (unsigned int*)w;   w += (size_t)E * 4;
  unsigned short* xwb = (unsigned short*)w; w += (size_t)N * D * 2;  // bf16 GEMM out
  unsigned short* P0hi = (unsigned short*)w; w += (size_t)N * D * 2; // ping-pong planes
  unsigned short* P0lo = (unsigned short*)w; w += (size_t)N * D * 2;
  unsigned short* P1hi = (unsigned short*)w; w += (size_t)N * D * 2;
  unsigned short* P1lo = (unsigned short*)w; w += (size_t)N * D * 2;
  float* hOut = (float*)P0hi;  // alias: P0 planes dead after gemm3 (25.6 MB = P0hi+P0lo)

  // ---- graph build + prep ----
  hipMemsetAsync(degcnt, 0, (size_t)N * 8, stream);
  deg_count_kernel<<<(E + 255) / 256, 256, 0, stream>>>(ew, dst, degcnt);
  scan_reduce_kernel<<<NB, 256, 0, stream>>>((const uint2*)degcnt, bsum, dinv);
  scan_bsum_kernel<<<1, 256, 0, stream>>>(bsum);
  scan_apply_kernel<<<NB, 256, 0, stream>>>((const uint2*)degcnt, bsum, offs, cursor);
  fill_kernel<<<(E + 255) / 256, 256, 0, stream>>>(src, dst, ew, dinv, cursor, csr);
  wprep_kernel<<<256, 256, 0, stream>>>(W1, W2, W3, Wh, wt);
  split_kernel<<<N * D / 8 / 256, 256, 0, stream>>>(x, P0hi, P0lo);  // 3125 blocks exact

  const int GB = (N + 127) / 128;  // 391 gemm blocks
  const int AG = N * 16 / 256;     // 3125 agg blocks

  // layer 1: P0 -> xwb -> P1
  gemm_mfma_kernel<<<GB, 256, 0, stream>>>(P0hi, P0lo, wt + 0 * 32768, nullptr, xwb, 0, 1);
  agg_kernel<<<AG, 256, 0, stream>>>(xwb, csr, offs, dinv, b1, P1hi, P1lo);
  // layer 2: P1 -> xwb -> P0
  gemm_mfma_kernel<<<GB, 256, 0, stream>>>(P1hi, P1lo, wt + 1 * 32768, nullptr, xwb, 0, 1);
  agg_kernel<<<AG, 256, 0, stream>>>(xwb, csr, offs, dinv, b2, P0hi, P0lo);
  // layer 3: P0 -> xwb -> P1
  gemm_mfma_kernel<<<GB, 256, 0, stream>>>(P0hi, P0lo, wt + 2 * 32768, nullptr, xwb, 0, 1);
  agg_kernel<<<AG, 256, 0, stream>>>(xwb, csr, offs, dinv, b3, P1hi, P1lo);
  // dense head layer: hOut = relu(P1 @ Wh + bh), fp32 (hOut aliases P0 region)
  gemm_mfma_kernel<<<GB, 256, 0, stream>>>(P1hi, P1lo, wt + 3 * 32768, bh, hOut, 1, 0);
  // heads
  heads_kernel<<<2 * T, 64, 0, stream>>>(hOut, ace, h2, Wace, bace, Wh2, bh2, (float*)d_out);
}

// Round 8
// 316.747 us; speedup vs baseline: 1.2632x; 1.1044x over previous
//
#include <hip/hip_runtime.h>
#include <math.h>

constexpr int N = 50000;   // nodes
constexpr int E = 640000;  // edges
constexpr int D = 128;     // dim == hidden
constexpr int T = 100;     // targets per head
constexpr int NB = (N + 255) / 256;  // 196 scan blocks

typedef __attribute__((ext_vector_type(8))) short short8;            // 8 bf16 in 4 VGPRs
typedef __attribute__((ext_vector_type(8))) unsigned short ushort8v;
typedef __attribute__((ext_vector_type(4))) float f32x4;             // MFMA accumulator

// ---------------- bf16 helpers (RNE) ----------------

__device__ inline unsigned short bf16_rne(float f) {
  unsigned int u = __float_as_uint(f);
  u += 0x7fff + ((u >> 16) & 1);
  return (unsigned short)(u >> 16);
}
__device__ inline float bf16_f32(unsigned short h) {
  return __uint_as_float((unsigned int)h << 16);
}

// ---------------- fused degree+count histogram: ONE 64-bit atomic per edge ----------------

__global__ void deg_count_kernel(const float* __restrict__ ew, const int* __restrict__ dst,
                                 unsigned long long* __restrict__ degcnt) {
  int e = blockIdx.x * 256 + threadIdx.x;
  if (e < E) {
    unsigned int fx = (unsigned int)__float2uint_rn(ew[e] * 16777216.0f);
    atomicAdd(&degcnt[dst[e]], ((unsigned long long)fx << 32) | 1ull);
  }
}

// ---------------- scan phase 1 (+ dinv folded in) ----------------

__global__ __launch_bounds__(256) void scan_reduce_kernel(const uint2* __restrict__ degcnt,
                                                          int* __restrict__ bsum,
                                                          float* __restrict__ dinv) {
  __shared__ int part[256];
  int t = threadIdx.x;
  int i = blockIdx.x * 256 + t;
  int c = 0;
  if (i < N) {
    uint2 p = degcnt[i];
    c = (int)p.x;
    float d = (float)p.y * (1.0f / 16777216.0f) + 1.0f;  // +1 self-loop
    dinv[i] = 1.0f / sqrtf(d);
  }
  part[t] = c;
  __syncthreads();
#pragma unroll
  for (int off = 128; off; off >>= 1) {
    if (t < off) part[t] += part[t + off];
    __syncthreads();
  }
  if (t == 0) bsum[blockIdx.x] = part[0];
}

// scan_apply: every block redundantly scans the 196 raw block sums in LDS
// (removes the serializing single-block middle kernel), then applies.

__global__ __launch_bounds__(256) void scan_apply_kernel(const uint2* __restrict__ degcnt,
                                                         const int* __restrict__ bsum,
                                                         int* __restrict__ offs,
                                                         int* __restrict__ cursor) {
  __shared__ int sb[256];
  __shared__ int part[256];
  int t = threadIdx.x;
  int i = blockIdx.x * 256 + t;
  sb[t] = (t < NB) ? bsum[t] : 0;
  int c = (i < N) ? (int)degcnt[i].x : 0;
  part[t] = c;
  __syncthreads();
#pragma unroll
  for (int off = 1; off < 256; off <<= 1) {
    int u1 = (t >= off) ? sb[t - off] : 0;
    int u2 = (t >= off) ? part[t - off] : 0;
    __syncthreads();
    sb[t] += u1;
    part[t] += u2;
    __syncthreads();
  }
  int base = (blockIdx.x == 0) ? 0 : sb[blockIdx.x - 1];
  if (i < N) {
    int o = base + part[t] - c;  // exclusive
    offs[i] = o;
    cursor[i] = o;
  }
  if (i == 0) offs[N] = E;
}

// ---------------- CSR fill: 4-byte entry = (coef 0.16-fixed << 16) | src(u16) ----------------

__global__ void fill_kernel(const int* __restrict__ src, const int* __restrict__ dst,
                            const float* __restrict__ ew, const float* __restrict__ dinv,
                            int* __restrict__ cursor, unsigned int* __restrict__ csr) {
  int e = blockIdx.x * 256 + threadIdx.x;
  if (e < E) {
    int s = src[e], d = dst[e];
    float c = dinv[s] * ew[e] * dinv[d];  // in [0,1)
    unsigned int fx = __float2uint_rn(c * 65536.0f);
    if (fx > 65535u) fx = 65535u;
    int pos = atomicAdd(&cursor[d], 1);
    csr[pos] = (fx << 16) | (unsigned int)s;
  }
}

// ---------------- W prep: fp32 W[k][n] -> bf16 hi/lo transposed Wt[n][k], 3 layers ----------------

__global__ void wprep_kernel(const float* __restrict__ W0, const float* __restrict__ W1,
                             const float* __restrict__ W2, unsigned short* __restrict__ wt) {
  int idx = blockIdx.x * 256 + threadIdx.x;  // 0..49151
  int layer = idx >> 14;
  int r = idx & 16383;
  int k = r & 127, n = r >> 7;
  const float* W = layer == 0 ? W0 : layer == 1 ? W1 : W2;
  float v = W[k * D + n];
  unsigned short hi = bf16_rne(v);
  unsigned short lo = bf16_rne(v - bf16_f32(hi));
  unsigned short* dstp = wt + layer * 2 * 16384;
  dstp[n * D + k] = hi;
  dstp[16384 + n * D + k] = lo;
}

// ---------------- shared MFMA core: B (hi+lo) in LDS, 128 rows/block, 4 waves ----------------
// LDS: 2 planes x 128 rows x stride 136 bf16 = 69632 B -> 2 blocks/CU.
// A.B = Ahi.Bhi + Alo.Bhi + Ahi.Blo. Output always bf16 (feeds agg).

__device__ inline void stage_B(const unsigned short* __restrict__ Wt,
                               unsigned short* __restrict__ Bl, int tid) {
  constexpr int SB = 136;
#pragma unroll
  for (int it = 0; it < 16; ++it) {
    int idx = tid + it * 256;          // ushort8 index, 0..4095
    int plane = idx >> 11;
    int r = (idx & 2047) >> 4;
    int c8 = idx & 15;
    ushort8v v = *(const ushort8v*)&Wt[plane * 16384 + r * D + c8 * 8];
    *(ushort8v*)&Bl[plane * 128 * SB + r * SB + c8 * 8] = v;
  }
}

__device__ inline void mfma_core_and_store(
    const unsigned short* __restrict__ Bl, short8 (*ah)[2], short8 (*al)[2],
    int row0, int rbase, int q, int n16, unsigned short* __restrict__ out) {
  constexpr int SB = 136;
  f32x4 acc[2][8] = {};
#pragma unroll
  for (int kc = 0; kc < 4; ++kc) {
    const int ko = kc * 32 + q * 8;
#pragma unroll
    for (int ct = 0; ct < 8; ++ct) {
      int n = ct * 16 + n16;
      short8 bh = *(const short8*)&Bl[n * SB + ko];
      short8 bl = *(const short8*)&Bl[128 * SB + n * SB + ko];
#pragma unroll
      for (int rt = 0; rt < 2; ++rt) {
        acc[rt][ct] = __builtin_amdgcn_mfma_f32_16x16x32_bf16(ah[kc][rt], bh, acc[rt][ct], 0, 0, 0);
        acc[rt][ct] = __builtin_amdgcn_mfma_f32_16x16x32_bf16(al[kc][rt], bh, acc[rt][ct], 0, 0, 0);
        acc[rt][ct] = __builtin_amdgcn_mfma_f32_16x16x32_bf16(ah[kc][rt], bl, acc[rt][ct], 0, 0, 0);
      }
    }
  }
  // epilogue: C/D layout col=lane&15, row=(lane>>4)*4+reg
#pragma unroll
  for (int rt = 0; rt < 2; ++rt) {
#pragma unroll
    for (int r = 0; r < 4; ++r) {
      int gr = row0 + rbase + rt * 16 + q * 4 + r;
      if (gr < N) {
#pragma unroll
        for (int ct = 0; ct < 8; ++ct) {
          int col = ct * 16 + n16;
          out[(size_t)gr * D + col] = bf16_rne(acc[rt][ct][r]);
        }
      }
    }
  }
}

// A from bf16 hi/lo planes (layers 2,3)
__global__ __launch_bounds__(256) void gemm_mfma_kernel(
    const unsigned short* __restrict__ Ahi, const unsigned short* __restrict__ Alo,
    const unsigned short* __restrict__ Wt, unsigned short* __restrict__ out) {
  constexpr int SB = 136;
  __shared__ unsigned short Bl[2 * 128 * SB];
  const int tid = threadIdx.x;
  const int row0 = blockIdx.x * 128;
  stage_B(Wt, Bl, tid);
  __syncthreads();

  const int w = tid >> 6, lane = tid & 63;
  const int q = lane >> 4, n16 = lane & 15;
  const int rbase = w * 32;
  size_t arow[2];
#pragma unroll
  for (int rt = 0; rt < 2; ++rt) {
    int gr = row0 + rbase + rt * 16 + n16;
    if (gr >= N) gr = N - 1;
    arow[rt] = (size_t)gr * D;
  }
  short8 ah[4][2], al[4][2];
#pragma unroll
  for (int kc = 0; kc < 4; ++kc) {
    const int ko = kc * 32 + q * 8;
#pragma unroll
    for (int rt = 0; rt < 2; ++rt) {
      ah[kc][rt] = *(const short8*)&Ahi[arow[rt] + ko];
      al[kc][rt] = *(const short8*)&Alo[arow[rt] + ko];
    }
  }
  mfma_core_and_store(Bl, ah, al, row0, rbase, q, n16, out);
}

// A from fp32 (layer 1: x), split in registers — no split_kernel pass.
__global__ __launch_bounds__(256) void gemm_mfma_f32_kernel(
    const float* __restrict__ A, const unsigned short* __restrict__ Wt,
    unsigned short* __restrict__ out) {
  constexpr int SB = 136;
  __shared__ unsigned short Bl[2 * 128 * SB];
  const int tid = threadIdx.x;
  const int row0 = blockIdx.x * 128;
  stage_B(Wt, Bl, tid);
  __syncthreads();

  const int w = tid >> 6, lane = tid & 63;
  const int q = lane >> 4, n16 = lane & 15;
  const int rbase = w * 32;
  size_t arow[2];
#pragma unroll
  for (int rt = 0; rt < 2; ++rt) {
    int gr = row0 + rbase + rt * 16 + n16;
    if (gr >= N) gr = N - 1;
    arow[rt] = (size_t)gr * D;
  }
  short8 ah[4][2], al[4][2];
#pragma unroll
  for (int kc = 0; kc < 4; ++kc) {
    const int ko = kc * 32 + q * 8;
#pragma unroll
    for (int rt = 0; rt < 2; ++rt) {
      float4 v0 = *(const float4*)&A[arow[rt] + ko];
      float4 v1 = *(const float4*)&A[arow[rt] + ko + 4];
      float v[8] = {v0.x, v0.y, v0.z, v0.w, v1.x, v1.y, v1.z, v1.w};
#pragma unroll
      for (int j = 0; j < 8; ++j) {
        unsigned short h = bf16_rne(v[j]);
        ah[kc][rt][j] = (short)h;
        al[kc][rt][j] = (short)bf16_rne(v[j] - bf16_f32(h));
      }
    }
  }
  mfma_core_and_store(Bl, ah, al, row0, rbase, q, n16, out);
}

// ---------------- pull aggregation over bf16 xw; writes bf16 hi/lo planes ----------------

__global__ __launch_bounds__(256) void agg_kernel(
    const unsigned short* __restrict__ xwb, const unsigned int* __restrict__ csr,
    const int* __restrict__ offs, const float* __restrict__ dinv,
    const float* __restrict__ bias, unsigned short* __restrict__ ohi,
    unsigned short* __restrict__ olo) {
  int g = (blockIdx.x * 256 + threadIdx.x) >> 4;  // node; 16 nodes/block
  int lane = threadIdx.x & 15;

  float dv = dinv[g];
  float s = dv * dv;
  ushort8v xv = *(const ushort8v*)&xwb[(size_t)g * D + lane * 8];
  float acc[8];
#pragma unroll
  for (int i = 0; i < 8; ++i)
    acc[i] = fmaf(s, bf16_f32(xv[i]), bias[lane * 8 + i]);

  int e = offs[g], e1 = offs[g + 1];
  for (; e + 2 <= e1; e += 2) {
    unsigned int p0 = csr[e], p1 = csr[e + 1];
    float c0 = (float)(p0 >> 16) * (1.0f / 65536.0f);
    float c1 = (float)(p1 >> 16) * (1.0f / 65536.0f);
    ushort8v v0 = *(const ushort8v*)&xwb[(size_t)(p0 & 0xffffu) * D + lane * 8];
    ushort8v v1 = *(const ushort8v*)&xwb[(size_t)(p1 & 0xffffu) * D + lane * 8];
#pragma unroll
    for (int i = 0; i < 8; ++i) {
      acc[i] = fmaf(c0, bf16_f32(v0[i]), acc[i]);
      acc[i] = fmaf(c1, bf16_f32(v1[i]), acc[i]);
    }
  }
  if (e < e1) {
    unsigned int p = csr[e];
    float c = (float)(p >> 16) * (1.0f / 65536.0f);
    ushort8v v = *(const ushort8v*)&xwb[(size_t)(p & 0xffffu) * D + lane * 8];
#pragma unroll
    for (int i = 0; i < 8; ++i) acc[i] = fmaf(c, bf16_f32(v[i]), acc[i]);
  }

  ushort8v hv, lv;
#pragma unroll
  for (int i = 0; i < 8; ++i) {
    float v = fmaxf(acc[i], 0.f);
    hv[i] = bf16_rne(v);
    lv[i] = bf16_rne(v - bf16_f32(hv[i]));
  }
  *(ushort8v*)&ohi[(size_t)g * D + lane * 8] = hv;
  *(ushort8v*)&olo[(size_t)g * D + lane * 8] = lv;
}

// ---------------- fused dense layer + heads: only the <=200 target rows ----------------
// out[t] = relu(row @ Wh + bh) @ Whead + bhead, row = P1[node] (hi+lo), fp32 math.
// 128 threads/block; thread j owns column j of Wh.

__global__ __launch_bounds__(128) void heads_kernel(
    const unsigned short* __restrict__ Phi, const unsigned short* __restrict__ Plo,
    const int* __restrict__ ace_idx, const int* __restrict__ h2_idx,
    const float* __restrict__ Wh, const float* __restrict__ bh,
    const float* __restrict__ Wace, const float* __restrict__ bace,
    const float* __restrict__ Wh2, const float* __restrict__ bh2,
    float* __restrict__ out) {
  __shared__ float row[D];
  __shared__ float psum[2];
  int t = blockIdx.x;       // 0..2T-1
  int j = threadIdx.x;      // 0..127
  int node; const float* whead; float bhead;
  if (t < T) { node = ace_idx[t];     whead = Wace; bhead = bace[0]; }
  else       { node = h2_idx[t - T];  whead = Wh2;  bhead = bh2[0]; }

  row[j] = bf16_f32(Phi[(size_t)node * D + j]) + bf16_f32(Plo[(size_t)node * D + j]);
  __syncthreads();

  float acc = bh[j];
#pragma unroll 16
  for (int k = 0; k < D; ++k)
    acc = fmaf(row[k], Wh[k * D + j], acc);
  float v = fmaxf(acc, 0.f) * whead[j];

  // reduce 128 values: wave shuffle then cross-wave via LDS
#pragma unroll
  for (int off = 32; off; off >>= 1) v += __shfl_down(v, off, 64);
  if ((j & 63) == 0) psum[j >> 6] = v;
  __syncthreads();
  if (j == 0) out[t] = psum[0] + psum[1] + bhead;
}

// ---------------- launch ----------------

extern "C" void kernel_launch(void* const* d_in, const int* in_sizes, int n_in,
                              void* d_out, int out_size, void* d_ws, size_t ws_size,
                              hipStream_t stream) {
  const float* x    = (const float*)d_in[0];
  const int*   ei   = (const int*)d_in[1];
  const float* ew   = (const float*)d_in[2];
  const int*   ace  = (const int*)d_in[3];
  const int*   h2   = (const int*)d_in[4];
  const float* W1 = (const float*)d_in[5];  const float* b1 = (const float*)d_in[6];
  const float* W2 = (const float*)d_in[7];  const float* b2 = (const float*)d_in[8];
  const float* W3 = (const float*)d_in[9];  const float* b3 = (const float*)d_in[10];
  const float* Wh = (const float*)d_in[11]; const float* bh = (const float*)d_in[12];
  const float* Wace = (const float*)d_in[13]; const float* bace = (const float*)d_in[14];
  const float* Wh2  = (const float*)d_in[15]; const float* bh2  = (const float*)d_in[16];
  const int* src = ei;
  const int* dst = ei + E;

  // workspace layout (16B-aligned blocks); ~67 MB total
  char* w = (char*)d_ws;
  unsigned long long* degcnt = (unsigned long long*)w;  w += (size_t)N * 8;  // zeroed
  float* dinv   = (float*)w;              w += N * 4;
  int*   offs   = (int*)w;                w += (N + 4) * 4;
  int*   cursor = (int*)w;                w += N * 4;
  int*   bsum   = (int*)w;                w += 256 * 4;
  unsigned short* wt = (unsigned short*)w; w += 3 * 2 * 16384 * 2;   // 3 layers hi/lo bf16
  unsigned int* csr = (unsigned int*)w;   w += (size_t)E * 4;
  unsigned short* xwb = (unsigned short*)w; w += (size_t)N * D * 2;  // bf16 GEMM out
  unsigned short* P0hi = (unsigned short*)w; w += (size_t)N * D * 2; // ping-pong planes
  unsigned short* P0lo = (unsigned short*)w; w += (size_t)N * D * 2;
  unsigned short* P1hi = (unsigned short*)w; w += (size_t)N * D * 2;
  unsigned short* P1lo = (unsigned short*)w; w += (size_t)N * D * 2;

  // ---- graph build + prep ----
  hipMemsetAsync(degcnt, 0, (size_t)N * 8, stream);
  deg_count_kernel<<<(E + 255) / 256, 256, 0, stream>>>(ew, dst, degcnt);
  scan_reduce_kernel<<<NB, 256, 0, stream>>>((const uint2*)degcnt, bsum, dinv);
  scan_apply_kernel<<<NB, 256, 0, stream>>>((const uint2*)degcnt, bsum, offs, cursor);
  fill_kernel<<<(E + 255) / 256, 256, 0, stream>>>(src, dst, ew, dinv, cursor, csr);
  wprep_kernel<<<192, 256, 0, stream>>>(W1, W2, W3, wt);

  const int GB = (N + 127) / 128;  // 391 gemm blocks
  const int AG = N * 16 / 256;     // 3125 agg blocks

  // layer 1: x (fp32, in-register split) -> xwb -> P1
  gemm_mfma_f32_kernel<<<GB, 256, 0, stream>>>(x, wt + 0 * 32768, xwb);
  agg_kernel<<<AG, 256, 0, stream>>>(xwb, csr, offs, dinv, b1, P1hi, P1lo);
  // layer 2: P1 -> xwb -> P0
  gemm_mfma_kernel<<<GB, 256, 0, stream>>>(P1hi, P1lo, wt + 1 * 32768, xwb);
  agg_kernel<<<AG, 256, 0, stream>>>(xwb, csr, offs, dinv, b2, P0hi, P0lo);
  // layer 3: P0 -> xwb -> P1
  gemm_mfma_kernel<<<GB, 256, 0, stream>>>(P0hi, P0lo, wt + 2 * 32768, xwb);
  agg_kernel<<<AG, 256, 0, stream>>>(xwb, csr, offs, dinv, b3, P1hi, P1lo);
  // fused dense layer + heads: only target rows
  heads_kernel<<<2 * T, 128, 0, stream>>>(P1hi, P1lo, ace, h2, Wh, bh,
                                          Wace, bace, Wh2, bh2, (float*)d_out);
}